// Round 4
// baseline (233.446 us; speedup 1.0000x reference)
//
#include <hip/hip_runtime.h>
#include <hip/hip_fp16.h>
#include <stdint.h>

typedef float f32x4 __attribute__((ext_vector_type(4)));
typedef _Float16 f16x8 __attribute__((ext_vector_type(8)));
typedef unsigned short us8 __attribute__((ext_vector_type(8)));
typedef unsigned long long u64t;

#define EPS    2.5e-3f
#define QCAP   512
#define NSHARD 16

// ws layout (bytes)
#define WS_LOSSP 0        // float[512]
#define WS_MIND  2048     // u32[1024]
#define WS_ACT   6144     // int[1024]
#define WS_C2    10240    // float[1024]
#define WS_PCB   14336    // ushort[65536] fp16 frag-linear codebook
#define WS_SHARD 145408   // u32[16*1024]

__device__ __forceinline__ void gld16(const void* g, void* l) {
    __builtin_amdgcn_global_load_lds(
        (const __attribute__((address_space(1))) unsigned int*)g,
        (__attribute__((address_space(3))) unsigned int*)l,
        16, 0, 0);
}
__device__ __forceinline__ float hi_f(u64t v) {
    return __uint_as_float((unsigned)(v >> 32));
}
__device__ __forceinline__ u64t pack_dc(float d, unsigned c) {
    return ((u64t)__float_as_uint(d) << 32) | c;
}

// ---------------- k0: init + fp16 frag-linear codebook + c2 ----------------
__global__ __launch_bounds__(256) void vq_k0(const float* __restrict__ cb,
                                             unsigned* __restrict__ shard,
                                             int* __restrict__ active,
                                             float* __restrict__ c2,
                                             unsigned short* __restrict__ pcb) {
    int g = blockIdx.x * 256 + threadIdx.x;   // grid 64 -> 16384
    shard[g] = 0x7F800000u;
    if (g < 1024) {
        active[g] = 0;
        const float4* row = (const float4*)(cb + g * 64);
        float s = 0.f;
#pragma unroll
        for (int q = 0; q < 16; ++q) {
            float4 v = row[q];
            s = fmaf(v.x, v.x, s); s = fmaf(v.y, v.y, s);
            s = fmaf(v.z, v.z, s); s = fmaf(v.w, v.w, s);
        }
        c2[g] = s;
    }
    if (g < 8192) {   // unit = (code c, 8-elem d-chunk u)
        int c = g >> 3, u = g & 7;
        const float4* row = (const float4*)(cb + c * 64);
        float4 v0 = row[u * 2], v1 = row[u * 2 + 1];
        us8 o;
        o[0] = __half_as_ushort(__float2half_rn(v0.x));
        o[1] = __half_as_ushort(__float2half_rn(v0.y));
        o[2] = __half_as_ushort(__float2half_rn(v0.z));
        o[3] = __half_as_ushort(__float2half_rn(v0.w));
        o[4] = __half_as_ushort(__float2half_rn(v1.x));
        o[5] = __half_as_ushort(__float2half_rn(v1.y));
        o[6] = __half_as_ushort(__float2half_rn(v1.z));
        o[7] = __half_as_ushort(__float2half_rn(v1.w));
        int frag  = (c >> 4) * 2 + (u >> 2);
        int lane8 = (c & 15) + 16 * (u & 3);
        *(us8*)&pcb[frag * 512 + lane8 * 8] = o;
    }
}

// ---------------- k1: fp16-MFMA argmin + event-flag near-ties + exact rescore
//                      + fused straight-through output ----------------
__global__ __launch_bounds__(256, 2) void vq_k1(const float* __restrict__ x,
                                                const float* __restrict__ cb,
                                                const float* __restrict__ c2g,
                                                const unsigned short* __restrict__ pcb,
                                                unsigned* __restrict__ shard,
                                                int* __restrict__ active,
                                                float* __restrict__ outp,
                                                float* __restrict__ lossPartial) {
    __shared__ __align__(16) unsigned short aF[4096];       // 8KB fp16 x-frags
    __shared__ __align__(16) unsigned short cbF[2][8192];   // 2x16KB fp16 code tiles
    __shared__ float    c2s[1024];
    __shared__ float    mcode[1024];
    __shared__ float    x2s[64];
    __shared__ u64t     wred[256];
    __shared__ int      toks[64];
    __shared__ unsigned queue[QCAP];
    __shared__ unsigned qcount;

    const int tid  = threadIdx.x;
    const int lane = tid & 63;
    const int w    = tid >> 6;
    const int p0   = blockIdx.x * 64;
    const int rowb = ((lane >> 4) & 3) * 4;

    if (tid == 0) qcount = 0;

#define PUSH1(rw, cA) do { \
        unsigned ix_ = atomicAdd(&qcount, 1u); \
        if (ix_ < QCAP) queue[ix_] = ((unsigned)(rw) << 10) | (unsigned)(cA); \
    } while (0)
#define PUSH2(rw, cA, cB) do { \
        unsigned ix_ = atomicAdd(&qcount, 2u); \
        if (ix_ < QCAP)     queue[ix_]     = ((unsigned)(rw) << 10) | (unsigned)(cA); \
        if (ix_ + 1 < QCAP) queue[ix_ + 1] = ((unsigned)(rw) << 10) | (unsigned)(cB); \
    } while (0)

    // issue tile-0 stage immediately (overlaps conversion VALU)
    {
        const char* src = (const char*)pcb;
        char* dst = (char*)&cbF[0][0];
#pragma unroll
        for (int it = 0; it < 4; ++it)
            gld16(src + it * 4096 + w * 1024 + (size_t)lane * 16,
                  dst + it * 4096 + w * 1024 + lane * 16);
    }

    // stage x -> fp16 frag-linear + x2 (thread: row=tid>>2, 16 elems at 16*(tid&3))
    {
        int r = tid >> 2, sg = tid & 3;
        const float4* xr4 = (const float4*)(x + (size_t)(p0 + r) * 64) + sg * 4;
        float4 v0 = xr4[0], v1 = xr4[1], v2 = xr4[2], v3 = xr4[3];
        float s = 0.f;
        s = fmaf(v0.x, v0.x, s); s = fmaf(v0.y, v0.y, s); s = fmaf(v0.z, v0.z, s); s = fmaf(v0.w, v0.w, s);
        s = fmaf(v1.x, v1.x, s); s = fmaf(v1.y, v1.y, s); s = fmaf(v1.z, v1.z, s); s = fmaf(v1.w, v1.w, s);
        s = fmaf(v2.x, v2.x, s); s = fmaf(v2.y, v2.y, s); s = fmaf(v2.z, v2.z, s); s = fmaf(v2.w, v2.w, s);
        s = fmaf(v3.x, v3.x, s); s = fmaf(v3.y, v3.y, s); s = fmaf(v3.z, v3.z, s); s = fmaf(v3.w, v3.w, s);
        s += __shfl_xor(s, 1);
        s += __shfl_xor(s, 2);
        if (sg == 0) x2s[r] = s;

        us8 o0, o1;
        o0[0]=__half_as_ushort(__float2half_rn(v0.x)); o0[1]=__half_as_ushort(__float2half_rn(v0.y));
        o0[2]=__half_as_ushort(__float2half_rn(v0.z)); o0[3]=__half_as_ushort(__float2half_rn(v0.w));
        o0[4]=__half_as_ushort(__float2half_rn(v1.x)); o0[5]=__half_as_ushort(__float2half_rn(v1.y));
        o0[6]=__half_as_ushort(__float2half_rn(v1.z)); o0[7]=__half_as_ushort(__float2half_rn(v1.w));
        o1[0]=__half_as_ushort(__float2half_rn(v2.x)); o1[1]=__half_as_ushort(__float2half_rn(v2.y));
        o1[2]=__half_as_ushort(__float2half_rn(v2.z)); o1[3]=__half_as_ushort(__float2half_rn(v2.w));
        o1[4]=__half_as_ushort(__float2half_rn(v3.x)); o1[5]=__half_as_ushort(__float2half_rn(v3.y));
        o1[6]=__half_as_ushort(__float2half_rn(v3.z)); o1[7]=__half_as_ushort(__float2half_rn(v3.w));
        int u0 = 2 * sg, u1 = 2 * sg + 1;
        int f0 = (r >> 4) * 2 + (u0 >> 2), l0 = (r & 15) + 16 * (u0 & 3);
        int f1 = (r >> 4) * 2 + (u1 >> 2), l1 = (r & 15) + 16 * (u1 & 3);
        *(us8*)&aF[f0 * 512 + l0 * 8] = o0;
        *(us8*)&aF[f1 * 512 + l1 * 8] = o1;
    }
#pragma unroll
    for (int q = 0; q < 4; ++q) c2s[tid + q * 256] = c2g[tid + q * 256];
    __syncthreads();   // aF/x2s/c2s ready; tile-0 drained

    f16x8 a[4][2];
#pragma unroll
    for (int rf = 0; rf < 4; ++rf)
#pragma unroll
        for (int kk = 0; kk < 2; ++kk)
            a[rf][kk] = *(const f16x8*)&aF[(rf * 2 + kk) * 512 + lane * 8];

    float x2r[16];
#pragma unroll
    for (int rf = 0; rf < 4; ++rf)
#pragma unroll
        for (int i = 0; i < 4; ++i)
            x2r[rf * 4 + i] = x2s[rf * 16 + rowb + i];

    u64t m1[16];
#pragma unroll
    for (int r = 0; r < 16; ++r) m1[r] = 0x7F800000FFFFFFFFull;

    for (int t = 0; t < 8; ++t) {
        const int cur = t & 1;
        if (t < 7) {   // prefetch next tile into the other buffer
            const char* src = (const char*)pcb + (t + 1) * 16384;
            char* dst = (char*)&cbF[cur ^ 1][0];
#pragma unroll
            for (int it = 0; it < 4; ++it)
                gld16(src + it * 4096 + w * 1024 + (size_t)lane * 16,
                      dst + it * 4096 + w * 1024 + lane * 16);
        }

        f32x4 acc[4][2];
#pragma unroll
        for (int rf = 0; rf < 4; ++rf)
#pragma unroll
            for (int cf = 0; cf < 2; ++cf)
                acc[rf][cf] = (f32x4){0.f, 0.f, 0.f, 0.f};

#pragma unroll
        for (int cf = 0; cf < 2; ++cf)
#pragma unroll
            for (int kk = 0; kk < 2; ++kk) {
                f16x8 b = *(const f16x8*)&cbF[cur][(((cf * 4 + w) * 2) + kk) * 512 + lane * 8];
#pragma unroll
                for (int rf = 0; rf < 4; ++rf)
                    acc[rf][cf] = __builtin_amdgcn_mfma_f32_16x16x32_f16(
                        a[rf][kk], b, acc[rf][cf], 0, 0, 0);
            }

        // epilogue: dist, running u64 min with near-tie events, per-code min
#pragma unroll
        for (int cf = 0; cf < 2; ++cf) {
            const unsigned cg = t * 128 + (cf * 4 + w) * 16 + (lane & 15);
            const float c2v = c2s[cg];
            float pcm = 3.4e38f;
#pragma unroll
            for (int rf = 0; rf < 4; ++rf)
#pragma unroll
                for (int i = 0; i < 4; ++i) {
                    const int r = rf * 4 + i;
                    float d = fmaf(-2.0f, acc[rf][cf][i], x2r[r]) + c2v;
                    float mo = hi_f(m1[r]);
                    if (fabsf(d - mo) <= EPS)   // near-tie event (rare)
                        PUSH2(rf * 16 + rowb + i, cg, (unsigned)(m1[r] & 1023u));
                    u64t pk = pack_dc(d, cg);
                    if (pk < m1[r]) m1[r] = pk;
                    pcm = fminf(pcm, d);
                }
            pcm = fminf(pcm, __shfl_xor(pcm, 16));
            pcm = fminf(pcm, __shfl_xor(pcm, 32));
            if (lane < 16) mcode[cg] = pcm;   // unique writer per code
        }
        __syncthreads();   // tile consumed; prefetch drained
    }

    // butterfly merge across the 16 code-lanes, with near-tie events
#pragma unroll
    for (int s = 1; s < 16; s <<= 1) {
#pragma unroll
        for (int r = 0; r < 16; ++r) {
            u64t o = __shfl_xor(m1[r], s);
            if (fabsf(hi_f(o) - hi_f(m1[r])) <= EPS)
                PUSH1(((r >> 2) * 16 + rowb + (r & 3)),
                      (unsigned)(((o < m1[r]) ? m1[r] : o) & 1023u));
            if (o < m1[r]) m1[r] = o;
        }
    }
    if ((lane & 15) == 0) {
#pragma unroll
        for (int rf = 0; rf < 4; ++rf)
#pragma unroll
            for (int i = 0; i < 4; ++i)
                wred[w * 64 + rf * 16 + rowb + i] = m1[rf * 4 + i];
    }
    __syncthreads();   // (A) wred visible

    u64t b = ~0ull;
    if (tid < 64) {
        b = wred[tid];
#pragma unroll
        for (int q = 1; q < 4; ++q) {
            u64t o = wred[q * 64 + tid];
            if (fabsf(hi_f(o) - hi_f(b)) <= EPS)
                PUSH1(tid, (unsigned)(((o < b) ? b : o) & 1023u));
            if (o < b) b = o;
        }
    }
    __syncthreads();   // (B) all pushes done; qcount final

    // wave 0: scan queue, exact-rescore flagged rows; others: flush mcode
    unsigned qc = qcount; if (qc > QCAP) qc = QCAP;
    if (tid < 64) {
        bool fl = false;
        for (unsigned q = 0; q < qc; ++q) fl |= ((queue[q] >> 10) == (unsigned)tid);
        unsigned cfin = (unsigned)(b & 1023u);
        float dfin = hi_f(b);
        if (fl) {   // exact fp32 rescore (reference-identical sequential fma)
            const float* xr = x + (size_t)(p0 + tid) * 64;
            float x2v = x2s[tid];
            {
                const float* cr = cb + (size_t)cfin * 64;
                float s = 0.f;
#pragma unroll
                for (int d = 0; d < 64; ++d) s = fmaf(xr[d], cr[d], s);
                dfin = (x2v - 2.f * s) + c2s[cfin];
            }
            u64t bx = pack_dc(dfin, cfin);
            for (unsigned q = 0; q < qc; ++q) {
                unsigned e = queue[q];
                if ((e >> 10) != (unsigned)tid) continue;
                unsigned c = e & 1023u;
                if (c == cfin) continue;
                const float* cr = cb + (size_t)c * 64;
                float s = 0.f;
#pragma unroll
                for (int d = 0; d < 64; ++d) s = fmaf(xr[d], cr[d], s);
                float de = (x2v - 2.f * s) + c2s[c];
                u64t p2 = pack_dc(de, c);
                if (p2 < bx) bx = p2;
            }
            cfin = (unsigned)(bx & 1023u);
            dfin = hi_f(bx);
        }
        toks[tid] = (int)cfin;
        atomicAdd(&active[cfin], 1);
        float s = dfin;
        s += __shfl_xor(s, 1);  s += __shfl_xor(s, 2);  s += __shfl_xor(s, 4);
        s += __shfl_xor(s, 8);  s += __shfl_xor(s, 16); s += __shfl_xor(s, 32);
        if (tid == 0) lossPartial[blockIdx.x] = s;
    }
    {   // per-code min flush (parallel with wave-0 rescore)
        const unsigned shbase = (blockIdx.x & (NSHARD - 1)) << 10;
#pragma unroll
        for (int q = 0; q < 4; ++q) {
            int c = tid + q * 256;
            atomicMin(&shard[shbase + c], __float_as_uint(mcode[c]));
        }
    }
    __syncthreads();   // (C) toks visible

    // fused straight-through output: out = x + (emb - x)
    {
        int pp = tid >> 2, sg = tid & 3;
        int tok = toks[pp];
        const f32x4* xr4 = (const f32x4*)(x + (size_t)(p0 + pp) * 64) + sg * 4;
        const f32x4* cr4 = (const f32x4*)(cb + (size_t)tok * 64) + sg * 4;
        f32x4* or4 = (f32x4*)(outp + (size_t)(p0 + pp) * 64) + sg * 4;
#pragma unroll
        for (int j = 0; j < 4; ++j) {
            f32x4 xv = xr4[j], cv = cr4[j];
            or4[j] = xv + (cv - xv);
        }
    }
#undef PUSH1
#undef PUSH2
}

// ---------------- k3a: merge shards ----------------
__global__ __launch_bounds__(256) void vq_k3a(const unsigned* __restrict__ shard,
                                              unsigned* __restrict__ minDist) {
    int c = blockIdx.x * 256 + threadIdx.x;   // grid 4
    unsigned m = 0x7F800000u;
#pragma unroll
    for (int s = 0; s < NSHARD; ++s) m = min(m, shard[s * 1024 + c]);
    minDist[c] = m;
}

// ---------------- k3: final loss ----------------
__global__ __launch_bounds__(1024) void vq_k3(const unsigned* __restrict__ minDist,
                                              const int* __restrict__ active,
                                              const float* __restrict__ lossPartial,
                                              float* __restrict__ out_loss) {
    __shared__ double red[1024];
    __shared__ double entS;
    int t = threadIdx.x;

    red[t] = (active[t] == 0) ? (double)__uint_as_float(minDist[t]) : 0.0;
    __syncthreads();
    for (int s = 512; s > 0; s >>= 1) {
        if (t < s) red[t] += red[t + s];
        __syncthreads();
    }
    if (t == 0) entS = red[0];
    __syncthreads();

    red[t] = (t < 512) ? (double)lossPartial[t] : 0.0;
    __syncthreads();
    for (int s = 512; s > 0; s >>= 1) {
        if (t < s) red[t] += red[t + s];
        __syncthreads();
    }
    if (t == 0) {
        double mean_sq = red[0] / (double)(32768ll * 64);
        double total = 1.25 * mean_sq + 0.01 * (entS / 1024.0);
        out_loss[0] = (float)total;
    }
}

extern "C" void kernel_launch(void* const* d_in, const int* in_sizes, int n_in,
                              void* d_out, int out_size, void* d_ws, size_t ws_size,
                              hipStream_t stream) {
    const float* x  = (const float*)d_in[0];
    const float* cb = (const float*)d_in[1];
    float* outp = (float*)d_out;
    char* ws = (char*)d_ws;

    float*          lossPartial = (float*)(ws + WS_LOSSP);
    unsigned*       minDist     = (unsigned*)(ws + WS_MIND);
    int*            active      = (int*)(ws + WS_ACT);
    float*          c2          = (float*)(ws + WS_C2);
    unsigned short* pcb         = (unsigned short*)(ws + WS_PCB);
    unsigned*       shard       = (unsigned*)(ws + WS_SHARD);

    vq_k0 <<<64,  256, 0, stream>>>(cb, shard, active, c2, pcb);
    vq_k1 <<<512, 256, 0, stream>>>(x, cb, c2, pcb, shard, active, outp, lossPartial);
    vq_k3a<<<4,   256, 0, stream>>>(shard, minDist);
    vq_k3 <<<1,  1024, 0, stream>>>(minDist, active, lossPartial, outp + 2097152);
}

// Round 5
// 76.105 us; speedup vs baseline: 3.0674x; 3.0674x over previous
//
#include <hip/hip_runtime.h>
#include <hip/hip_fp16.h>
#include <stdint.h>

typedef float f32x4 __attribute__((ext_vector_type(4)));
typedef _Float16 f16x8 __attribute__((ext_vector_type(8)));
typedef unsigned short us8 __attribute__((ext_vector_type(8)));
typedef unsigned long long u64t;

#define EPS    3.0e-3f
#define FCAP   8192
#define NSHARD 16

// ws layout (bytes)
#define WS_TOKEN 0        // int[32768]
#define WS_BDIST 131072   // float[32768]
#define WS_PCB   262144   // ushort[65536] fp16 frag-linear codebook
#define WS_CBT   393216   // float[65536] cb transposed [d][c]
#define WS_C2    655360   // float[1024]
#define WS_SHARD 659456   // u32[16*1024]
#define WS_MIND  724992   // u32[1024]
#define WS_ACT   729088   // int[1024]
#define WS_FLAG  733184   // int[8192]
#define WS_FCNT  765952   // u32[64]
#define WS_DPART 766208   // float[64]

__device__ __forceinline__ float hi_f(u64t v) {
    return __uint_as_float((unsigned)(v >> 32));
}

// ---------------- k0: init + fp16 frag-linear codebook + cbT + c2 ----------------
__global__ __launch_bounds__(256) void vq_k0(const float* __restrict__ cb,
                                             unsigned* __restrict__ shard,
                                             int* __restrict__ active,
                                             float* __restrict__ c2,
                                             unsigned short* __restrict__ pcb,
                                             float* __restrict__ cbT,
                                             unsigned* __restrict__ fcnt) {
    int g = blockIdx.x * 256 + threadIdx.x;   // grid 64 -> 16384
    shard[g] = 0x7F800000u;                   // 16*1024 entries exactly
    if (g < 64) fcnt[g] = 0;
    if (g < 1024) {
        active[g] = 0;
        const float4* row = (const float4*)(cb + g * 64);
        float s = 0.f;
#pragma unroll
        for (int q = 0; q < 16; ++q) {
            float4 v = row[q];
            s = fmaf(v.x, v.x, s); s = fmaf(v.y, v.y, s);
            s = fmaf(v.z, v.z, s); s = fmaf(v.w, v.w, s);
        }
        c2[g] = s;
    }
    if (g < 8192) {   // fp16 frag-linear: unit = (code c, 8-elem d-chunk u)
        int c = g >> 3, u = g & 7;
        const float4* row = (const float4*)(cb + c * 64);
        float4 v0 = row[u * 2], v1 = row[u * 2 + 1];
        us8 o;
        o[0] = __half_as_ushort(__float2half_rn(v0.x));
        o[1] = __half_as_ushort(__float2half_rn(v0.y));
        o[2] = __half_as_ushort(__float2half_rn(v0.z));
        o[3] = __half_as_ushort(__float2half_rn(v0.w));
        o[4] = __half_as_ushort(__float2half_rn(v1.x));
        o[5] = __half_as_ushort(__float2half_rn(v1.y));
        o[6] = __half_as_ushort(__float2half_rn(v1.z));
        o[7] = __half_as_ushort(__float2half_rn(v1.w));
        int frag  = (c >> 4) * 2 + (u >> 2);
        int lane8 = (c & 15) + 16 * (u & 3);
        *(us8*)&pcb[frag * 512 + lane8 * 8] = o;
    }
    {   // transpose: cbT[d][c] = cb[c][d]
        int c = g & 1023, seg = g >> 10;       // seg < 16, 4 d's each
        float4 v = ((const float4*)(cb + c * 64))[seg];
        cbT[(seg * 4 + 0) * 1024 + c] = v.x;
        cbT[(seg * 4 + 1) * 1024 + c] = v.y;
        cbT[(seg * 4 + 2) * 1024 + c] = v.z;
        cbT[(seg * 4 + 3) * 1024 + c] = v.w;
    }
}

// ---------------- k1: barrier-free fp16-MFMA argmin (16 pts/wave x 1024 codes) ----------------
__global__ __launch_bounds__(256, 4) void vq_k1(const float* __restrict__ x,
                                                const float* __restrict__ c2g,
                                                const unsigned short* __restrict__ pcb,
                                                unsigned* __restrict__ shard,
                                                int* __restrict__ token,
                                                float* __restrict__ bdist,
                                                int* __restrict__ gflag,
                                                unsigned* __restrict__ fcnt) {
    __shared__ __align__(16) unsigned short aF[4096];  // 8KB fp16 x-frags (64 pts)
    __shared__ float c2s[1024];
    __shared__ float x2s[64];
    __shared__ float mcode[4][1024];                   // per-wave per-code mins

    const int tid  = threadIdx.x;
    const int lane = tid & 63;
    const int w    = tid >> 6;
    const int col  = lane & 15;
    const int rg   = lane >> 4;
    const int p0   = blockIdx.x * 64;

    // stage x -> fp16 frag-linear LDS + split-assoc x2 (approx use only)
    {
        int r = tid >> 2, sg = tid & 3;
        const float4* xr4 = (const float4*)(x + (size_t)(p0 + r) * 64) + sg * 4;
        float4 v0 = xr4[0], v1 = xr4[1], v2 = xr4[2], v3 = xr4[3];
        float s = 0.f;
        s = fmaf(v0.x, v0.x, s); s = fmaf(v0.y, v0.y, s); s = fmaf(v0.z, v0.z, s); s = fmaf(v0.w, v0.w, s);
        s = fmaf(v1.x, v1.x, s); s = fmaf(v1.y, v1.y, s); s = fmaf(v1.z, v1.z, s); s = fmaf(v1.w, v1.w, s);
        s = fmaf(v2.x, v2.x, s); s = fmaf(v2.y, v2.y, s); s = fmaf(v2.z, v2.z, s); s = fmaf(v2.w, v2.w, s);
        s = fmaf(v3.x, v3.x, s); s = fmaf(v3.y, v3.y, s); s = fmaf(v3.z, v3.z, s); s = fmaf(v3.w, v3.w, s);
        s += __shfl_xor(s, 1);
        s += __shfl_xor(s, 2);
        if (sg == 0) x2s[r] = s;

        us8 o0, o1;
        o0[0]=__half_as_ushort(__float2half_rn(v0.x)); o0[1]=__half_as_ushort(__float2half_rn(v0.y));
        o0[2]=__half_as_ushort(__float2half_rn(v0.z)); o0[3]=__half_as_ushort(__float2half_rn(v0.w));
        o0[4]=__half_as_ushort(__float2half_rn(v1.x)); o0[5]=__half_as_ushort(__float2half_rn(v1.y));
        o0[6]=__half_as_ushort(__float2half_rn(v1.z)); o0[7]=__half_as_ushort(__float2half_rn(v1.w));
        o1[0]=__half_as_ushort(__float2half_rn(v2.x)); o1[1]=__half_as_ushort(__float2half_rn(v2.y));
        o1[2]=__half_as_ushort(__float2half_rn(v2.z)); o1[3]=__half_as_ushort(__float2half_rn(v2.w));
        o1[4]=__half_as_ushort(__float2half_rn(v3.x)); o1[5]=__half_as_ushort(__float2half_rn(v3.y));
        o1[6]=__half_as_ushort(__float2half_rn(v3.z)); o1[7]=__half_as_ushort(__float2half_rn(v3.w));
        int u0 = 2 * sg, u1 = 2 * sg + 1;
        int f0 = (r >> 4) * 2 + (u0 >> 2), l0 = (r & 15) + 16 * (u0 & 3);
        int f1 = (r >> 4) * 2 + (u1 >> 2), l1 = (r & 15) + 16 * (u1 & 3);
        *(us8*)&aF[f0 * 512 + l0 * 8] = o0;
        *(us8*)&aF[f1 * 512 + l1 * 8] = o1;
    }
#pragma unroll
    for (int q = 0; q < 4; ++q) c2s[tid + q * 256] = c2g[tid + q * 256];
    __syncthreads();   // barrier #1: aF/x2s/c2s ready

    // A frags for this wave's 16 points
    f16x8 a0 = *(const f16x8*)&aF[(w * 2 + 0) * 512 + lane * 8];
    f16x8 a1 = *(const f16x8*)&aF[(w * 2 + 1) * 512 + lane * 8];

    float x2r[4];
#pragma unroll
    for (int i = 0; i < 4; ++i) x2r[i] = x2s[w * 16 + rg * 4 + i];

    float    m1d[4], m2[4];
    unsigned m1c[4];
#pragma unroll
    for (int i = 0; i < 4; ++i) { m1d[i] = 3.4e38f; m2[i] = 3.4e38f; m1c[i] = 0; }

    const f16x8* pb = (const f16x8*)pcb;   // frag f at pb[f*64 + lane]

    // barrier-free main loop: 64 tiles of 16 codes
#pragma unroll 4
    for (int t = 0; t < 64; ++t) {
        f16x8 b0 = pb[(t * 2 + 0) * 64 + lane];
        f16x8 b1 = pb[(t * 2 + 1) * 64 + lane];
        f32x4 acc = (f32x4){0.f, 0.f, 0.f, 0.f};
        acc = __builtin_amdgcn_mfma_f32_16x16x32_f16(a0, b0, acc, 0, 0, 0);
        acc = __builtin_amdgcn_mfma_f32_16x16x32_f16(a1, b1, acc, 0, 0, 0);

        const float c2v = c2s[t * 16 + col];
        const unsigned code = (unsigned)(t * 16 + col);
        float pcm = 3.4e38f;
#pragma unroll
        for (int i = 0; i < 4; ++i) {
            float d = fmaf(-2.0f, acc[i], x2r[i]) + c2v;
            pcm = fminf(pcm, d);
            bool lt = d < m1d[i];                    // codes increase with t: ties keep old (lower)
            m2[i]  = fminf(m2[i], lt ? m1d[i] : d);  // loser of this comparison
            m1c[i] = lt ? code : m1c[i];
            m1d[i] = lt ? d : m1d[i];
        }
        pcm = fminf(pcm, __shfl_xor(pcm, 16));
        pcm = fminf(pcm, __shfl_xor(pcm, 32));
        if (lane < 16) mcode[w][t * 16 + lane] = pcm;   // wave-private, no atomic
    }

    // butterfly across the 16 code-lanes (lexicographic, first-index tie-break)
#pragma unroll
    for (int s = 1; s < 16; s <<= 1) {
#pragma unroll
        for (int i = 0; i < 4; ++i) {
            float    od  = __shfl_xor(m1d[i], s);
            unsigned oc  = (unsigned)__shfl_xor((int)m1c[i], s);
            float    om2 = __shfl_xor(m2[i], s);
            bool lt = (od < m1d[i]) || (od == m1d[i] && oc < m1c[i]);
            float lose = lt ? m1d[i] : od;
            m2[i]  = fminf(fminf(m2[i], om2), lose);
            m1d[i] = lt ? od : m1d[i];
            m1c[i] = lt ? oc : m1c[i];
        }
    }
    if (col == 0) {
#pragma unroll
        for (int i = 0; i < 4; ++i) {
            int p = p0 + w * 16 + rg * 4 + i;
            token[p] = (int)m1c[i];
            bdist[p] = m1d[i];
            if (m2[i] - m1d[i] <= EPS) {             // near-tie: exact resolution needed
                unsigned ix = atomicAdd(fcnt, 1u);
                if (ix < FCAP) gflag[ix] = p;
            }
        }
    }
    __syncthreads();   // barrier #2: mcode complete

    // merge per-wave per-code mins, flush to shard
    const unsigned shbase = (blockIdx.x & (NSHARD - 1)) << 10;
#pragma unroll
    for (int q = 0; q < 4; ++q) {
        int c = tid + q * 256;
        float m = fminf(fminf(mcode[0][c], mcode[1][c]),
                        fminf(mcode[2][c], mcode[3][c]));
        atomicMin(&shard[shbase + c], __float_as_uint(m));
    }
}

// ---------------- kfix: exact fp32 rescan for flagged points ----------------
__global__ __launch_bounds__(256) void vq_kfix(const float* __restrict__ x,
                                               const float* __restrict__ cbT,
                                               const float* __restrict__ c2,
                                               const int* __restrict__ gflag,
                                               const unsigned* __restrict__ fcnt,
                                               int* __restrict__ token,
                                               float* __restrict__ bdist) {
    __shared__ float xl[64];
    __shared__ u64t red[256];
    const int tid = threadIdx.x;
    unsigned nf = fcnt[0]; if (nf > FCAP) nf = FCAP;

    for (unsigned fi = blockIdx.x; fi < nf; fi += gridDim.x) {
        int p = gflag[fi];
        __syncthreads();
        if (tid < 64) xl[tid] = x[(size_t)p * 64 + tid];
        __syncthreads();
        // exact x2: sequential fma, reference-identical association
        float x2v = 0.f;
#pragma unroll
        for (int d = 0; d < 64; ++d) x2v = fmaf(xl[d], xl[d], x2v);
        float s0 = 0.f, s1 = 0.f, s2 = 0.f, s3 = 0.f;
#pragma unroll
        for (int d = 0; d < 64; ++d) {
            float xv = xl[d];
            s0 = fmaf(xv, cbT[d * 1024 +   0 + tid], s0);
            s1 = fmaf(xv, cbT[d * 1024 + 256 + tid], s1);
            s2 = fmaf(xv, cbT[d * 1024 + 512 + tid], s2);
            s3 = fmaf(xv, cbT[d * 1024 + 768 + tid], s3);
        }
        float d0 = (x2v - 2.f * s0) + c2[tid];
        float d1 = (x2v - 2.f * s1) + c2[tid + 256];
        float d2 = (x2v - 2.f * s2) + c2[tid + 512];
        float d3 = (x2v - 2.f * s3) + c2[tid + 768];
        u64t bb = ~0ull, pk;
        pk = ((u64t)__float_as_uint(d0) << 32) | (unsigned)(tid);       if (pk < bb) bb = pk;
        pk = ((u64t)__float_as_uint(d1) << 32) | (unsigned)(tid + 256); if (pk < bb) bb = pk;
        pk = ((u64t)__float_as_uint(d2) << 32) | (unsigned)(tid + 512); if (pk < bb) bb = pk;
        pk = ((u64t)__float_as_uint(d3) << 32) | (unsigned)(tid + 768); if (pk < bb) bb = pk;
        red[tid] = bb;
        __syncthreads();
        for (int s = 128; s > 0; s >>= 1) {
            if (tid < s) { u64t o = red[tid + s]; if (o < red[tid]) red[tid] = o; }
            __syncthreads();
        }
        if (tid == 0) {
            u64t b = red[0];
            token[p] = (int)(unsigned)(b & 0xFFFFFFFFu);
            bdist[p] = hi_f(b);
        }
    }
}

// ---------------- k2: straight-through output + active histogram ----------------
__global__ __launch_bounds__(256) void vq_k2(const float* __restrict__ x,
                                             const float* __restrict__ cb,
                                             const int* __restrict__ token,
                                             int* __restrict__ active,
                                             float* __restrict__ out) {
    int g = blockIdx.x * 256 + threadIdx.x;
    int p = g >> 4, q = g & 15;
    int tok = token[p];
    if (q == 0) atomicAdd(&active[tok], 1);
    float4 xv = reinterpret_cast<const float4*>(x)[g];
    float4 cv = reinterpret_cast<const float4*>(cb)[tok * 16 + q];
    float4 o;
    o.x = xv.x + (cv.x - xv.x);
    o.y = xv.y + (cv.y - xv.y);
    o.z = xv.z + (cv.z - xv.z);
    o.w = xv.w + (cv.w - xv.w);
    reinterpret_cast<float4*>(out)[g] = o;
}

// ---------------- k3a: merge shards ----------------
__global__ __launch_bounds__(256) void vq_k3a(const unsigned* __restrict__ shard,
                                              unsigned* __restrict__ minDist) {
    int c = blockIdx.x * 256 + threadIdx.x;   // grid 4
    unsigned m = 0x7F800000u;
#pragma unroll
    for (int s = 0; s < NSHARD; ++s) m = min(m, shard[s * 1024 + c]);
    minDist[c] = m;
}

// ---------------- k3b: partial sums of bdist ----------------
__global__ __launch_bounds__(256) void vq_k3b(const float* __restrict__ bdist,
                                              float* __restrict__ dpart) {
    __shared__ float red[256];
    const int tid = threadIdx.x;
    const float4* base = (const float4*)(bdist + blockIdx.x * 2048);   // grid 16
    float4 v0 = base[tid * 2], v1 = base[tid * 2 + 1];
    red[tid] = ((v0.x + v0.y) + (v0.z + v0.w)) + ((v1.x + v1.y) + (v1.z + v1.w));
    __syncthreads();
    for (int s = 128; s > 0; s >>= 1) {
        if (tid < s) red[tid] += red[tid + s];
        __syncthreads();
    }
    if (tid == 0) dpart[blockIdx.x] = red[0];
}

// ---------------- k3: final loss ----------------
__global__ __launch_bounds__(1024) void vq_k3(const unsigned* __restrict__ minDist,
                                              const int* __restrict__ active,
                                              const float* __restrict__ dpart,
                                              float* __restrict__ out_loss) {
    __shared__ double red[1024];
    __shared__ double entS;
    int t = threadIdx.x;

    red[t] = (active[t] == 0) ? (double)__uint_as_float(minDist[t]) : 0.0;
    __syncthreads();
    for (int s = 512; s > 0; s >>= 1) {
        if (t < s) red[t] += red[t + s];
        __syncthreads();
    }
    if (t == 0) entS = red[0];
    __syncthreads();

    red[t] = (t < 16) ? (double)dpart[t] : 0.0;
    __syncthreads();
    for (int s = 512; s > 0; s >>= 1) {
        if (t < s) red[t] += red[t + s];
        __syncthreads();
    }
    if (t == 0) {
        double mean_sq = red[0] / (double)(32768ll * 64);
        double total = 1.25 * mean_sq + 0.01 * (entS / 1024.0);
        out_loss[0] = (float)total;
    }
}

extern "C" void kernel_launch(void* const* d_in, const int* in_sizes, int n_in,
                              void* d_out, int out_size, void* d_ws, size_t ws_size,
                              hipStream_t stream) {
    const float* x  = (const float*)d_in[0];
    const float* cb = (const float*)d_in[1];
    float* out = (float*)d_out;
    char* ws = (char*)d_ws;

    int*            token   = (int*)(ws + WS_TOKEN);
    float*          bdist   = (float*)(ws + WS_BDIST);
    unsigned short* pcb     = (unsigned short*)(ws + WS_PCB);
    float*          cbT     = (float*)(ws + WS_CBT);
    float*          c2      = (float*)(ws + WS_C2);
    unsigned*       shard   = (unsigned*)(ws + WS_SHARD);
    unsigned*       minDist = (unsigned*)(ws + WS_MIND);
    int*            active  = (int*)(ws + WS_ACT);
    int*            gflag   = (int*)(ws + WS_FLAG);
    unsigned*       fcnt    = (unsigned*)(ws + WS_FCNT);
    float*          dpart   = (float*)(ws + WS_DPART);

    vq_k0  <<<64,   256, 0, stream>>>(cb, shard, active, c2, pcb, cbT, fcnt);
    vq_k1  <<<512,  256, 0, stream>>>(x, c2, pcb, shard, token, bdist, gflag, fcnt);
    vq_kfix<<<256,  256, 0, stream>>>(x, cbT, c2, gflag, fcnt, token, bdist);
    vq_k2  <<<2048, 256, 0, stream>>>(x, cb, token, active, out);
    vq_k3a <<<4,    256, 0, stream>>>(shard, minDist);
    vq_k3b <<<16,   256, 0, stream>>>(bdist, dpart);
    vq_k3  <<<1,   1024, 0, stream>>>(minDist, active, dpart, out + 2097152);
}

// Round 6
// 54.508 us; speedup vs baseline: 4.2828x; 1.3962x over previous
//
#include <hip/hip_runtime.h>
#include <hip/hip_fp16.h>
#include <stdint.h>

typedef float f32x4 __attribute__((ext_vector_type(4)));
typedef _Float16 f16x8 __attribute__((ext_vector_type(8)));
typedef unsigned short us8 __attribute__((ext_vector_type(8)));
typedef unsigned long long u64t;

#define EPS  3.0e-3f
#define FCAP 8192

// ws layout (bytes)
#define WS_M1D   0         // float[2][32768]  524288... (each half 131072B)
#define WS_M1C   262144    // int[2][32768]
#define WS_M2    524288    // float[2][32768]
#define WS_X2    786432    // float[32768]
#define WS_TOKEN 917504    // int[32768]
#define WS_BDIST 1048576   // float[32768]
#define WS_PCB   1179648   // ushort[65536] fp16 frag-linear codebook
#define WS_CBT   1310720   // float[65536] cb transposed [d][c]
#define WS_C2    1572864   // float[1024]
#define WS_SHARD 1576960   // u32[16*1024]
#define WS_ACT   1642496   // int[1024]
#define WS_FLAG  1646592   // int[8192]
#define WS_FCNT  1679360   // u32[64]

__device__ __forceinline__ float hi_f(u64t v) {
    return __uint_as_float((unsigned)(v >> 32));
}

// ---------------- k0: init + fp16 frag-linear codebook + cbT + c2 ----------------
__global__ __launch_bounds__(256) void vq_k0(const float* __restrict__ cb,
                                             unsigned* __restrict__ shard,
                                             int* __restrict__ active,
                                             float* __restrict__ c2,
                                             unsigned short* __restrict__ pcb,
                                             float* __restrict__ cbT,
                                             unsigned* __restrict__ fcnt) {
    int g = blockIdx.x * 256 + threadIdx.x;   // grid 64 -> 16384
    shard[g] = 0x7F800000u;                   // 16*1024 entries
    if (g < 64) fcnt[g] = 0;
    if (g < 1024) {
        active[g] = 0;
        const float4* row = (const float4*)(cb + g * 64);
        float s = 0.f;
#pragma unroll
        for (int q = 0; q < 16; ++q) {
            float4 v = row[q];
            s = fmaf(v.x, v.x, s); s = fmaf(v.y, v.y, s);
            s = fmaf(v.z, v.z, s); s = fmaf(v.w, v.w, s);
        }
        c2[g] = s;
    }
    if (g < 8192) {   // fp16 frag-linear: unit = (code c, 8-elem d-chunk u)
        int c = g >> 3, u = g & 7;
        const float4* row = (const float4*)(cb + c * 64);
        float4 v0 = row[u * 2], v1 = row[u * 2 + 1];
        us8 o;
        o[0] = __half_as_ushort(__float2half_rn(v0.x));
        o[1] = __half_as_ushort(__float2half_rn(v0.y));
        o[2] = __half_as_ushort(__float2half_rn(v0.z));
        o[3] = __half_as_ushort(__float2half_rn(v0.w));
        o[4] = __half_as_ushort(__float2half_rn(v1.x));
        o[5] = __half_as_ushort(__float2half_rn(v1.y));
        o[6] = __half_as_ushort(__float2half_rn(v1.z));
        o[7] = __half_as_ushort(__float2half_rn(v1.w));
        int frag  = (c >> 4) * 2 + (u >> 2);
        int lane8 = (c & 15) + 16 * (u & 3);
        *(us8*)&pcb[frag * 512 + lane8 * 8] = o;
    }
    {   // transpose: cbT[d][c] = cb[c][d]
        int c = g & 1023, seg = g >> 10;
        float4 v = ((const float4*)(cb + c * 64))[seg];
        cbT[(seg * 4 + 0) * 1024 + c] = v.x;
        cbT[(seg * 4 + 1) * 1024 + c] = v.y;
        cbT[(seg * 4 + 2) * 1024 + c] = v.z;
        cbT[(seg * 4 + 3) * 1024 + c] = v.w;
    }
}

// ---------------- k1: fp16-MFMA half-codebook argmin, shuffle-free inner loop ----------------
// grid 1024: block = (point-tile pt = bx>>1) x (code half h = bx&1). 16 waves/CU.
__global__ __launch_bounds__(256, 4) void vq_k1(const float* __restrict__ x,
                                                const float* __restrict__ c2g,
                                                const unsigned short* __restrict__ pcb,
                                                unsigned* __restrict__ shard,
                                                float* __restrict__ m1dA,
                                                int* __restrict__ m1cA,
                                                float* __restrict__ m2A,
                                                float* __restrict__ x2a) {
    __shared__ __align__(16) unsigned short aF[4096];  // 8KB fp16 x-frags (64 pts)
    __shared__ float    c2s[512];
    __shared__ float    x2s[64];
    __shared__ unsigned mcode[512];                    // per-block per-code min (full dist bits)

    const int tid  = threadIdx.x;
    const int lane = tid & 63;
    const int w    = tid >> 6;
    const int col  = lane & 15;
    const int rg   = lane >> 4;
    const int pt   = blockIdx.x >> 1;
    const int h    = blockIdx.x & 1;
    const int p0   = pt * 64;
    const int cb0  = h * 512;

    // stage x -> fp16 frag-linear LDS + x2 (split-assoc, approx path only)
    {
        int r = tid >> 2, sg = tid & 3;
        const float4* xr4 = (const float4*)(x + (size_t)(p0 + r) * 64) + sg * 4;
        float4 v0 = xr4[0], v1 = xr4[1], v2 = xr4[2], v3 = xr4[3];
        float s = 0.f;
        s = fmaf(v0.x, v0.x, s); s = fmaf(v0.y, v0.y, s); s = fmaf(v0.z, v0.z, s); s = fmaf(v0.w, v0.w, s);
        s = fmaf(v1.x, v1.x, s); s = fmaf(v1.y, v1.y, s); s = fmaf(v1.z, v1.z, s); s = fmaf(v1.w, v1.w, s);
        s = fmaf(v2.x, v2.x, s); s = fmaf(v2.y, v2.y, s); s = fmaf(v2.z, v2.z, s); s = fmaf(v2.w, v2.w, s);
        s = fmaf(v3.x, v3.x, s); s = fmaf(v3.y, v3.y, s); s = fmaf(v3.z, v3.z, s); s = fmaf(v3.w, v3.w, s);
        s += __shfl_xor(s, 1);
        s += __shfl_xor(s, 2);
        if (sg == 0) { x2s[r] = s; if (h == 0) x2a[p0 + r] = s; }

        us8 o0, o1;
        o0[0]=__half_as_ushort(__float2half_rn(v0.x)); o0[1]=__half_as_ushort(__float2half_rn(v0.y));
        o0[2]=__half_as_ushort(__float2half_rn(v0.z)); o0[3]=__half_as_ushort(__float2half_rn(v0.w));
        o0[4]=__half_as_ushort(__float2half_rn(v1.x)); o0[5]=__half_as_ushort(__float2half_rn(v1.y));
        o0[6]=__half_as_ushort(__float2half_rn(v1.z)); o0[7]=__half_as_ushort(__float2half_rn(v1.w));
        o1[0]=__half_as_ushort(__float2half_rn(v2.x)); o1[1]=__half_as_ushort(__float2half_rn(v2.y));
        o1[2]=__half_as_ushort(__float2half_rn(v2.z)); o1[3]=__half_as_ushort(__float2half_rn(v2.w));
        o1[4]=__half_as_ushort(__float2half_rn(v3.x)); o1[5]=__half_as_ushort(__float2half_rn(v3.y));
        o1[6]=__half_as_ushort(__float2half_rn(v3.z)); o1[7]=__half_as_ushort(__float2half_rn(v3.w));
        int u0 = 2 * sg, u1 = 2 * sg + 1;
        int f0 = (r >> 4) * 2 + (u0 >> 2), l0 = (r & 15) + 16 * (u0 & 3);
        int f1 = (r >> 4) * 2 + (u1 >> 2), l1 = (r & 15) + 16 * (u1 & 3);
        *(us8*)&aF[f0 * 512 + l0 * 8] = o0;
        *(us8*)&aF[f1 * 512 + l1 * 8] = o1;
    }
    c2s[tid]       = c2g[cb0 + tid];
    c2s[tid + 256] = c2g[cb0 + 256 + tid];
    mcode[tid]       = 0x7F800000u;
    mcode[tid + 256] = 0x7F800000u;
    __syncthreads();   // barrier #1

    f16x8 a0 = *(const f16x8*)&aF[(w * 2 + 0) * 512 + lane * 8];
    f16x8 a1 = *(const f16x8*)&aF[(w * 2 + 1) * 512 + lane * 8];

    float x2r[4];
#pragma unroll
    for (int i = 0; i < 4; ++i) x2r[i] = x2s[w * 16 + rg * 4 + i];

    float    m1d[4], m2r[4];
    unsigned m1c[4];
#pragma unroll
    for (int i = 0; i < 4; ++i) { m1d[i] = 3.4e38f; m2r[i] = 3.4e38f; m1c[i] = 0; }

    const f16x8* pb = (const f16x8*)pcb + (size_t)(h * 64) * 64;  // half base (tile h*32)

    // shuffle-free main loop: 32 tiles of 16 codes; per-code min via no-return LDS atomic
#pragma unroll 8
    for (int t = 0; t < 32; ++t) {
        f16x8 b0 = pb[(t * 2 + 0) * 64 + lane];
        f16x8 b1 = pb[(t * 2 + 1) * 64 + lane];
        f32x4 acc = (f32x4){0.f, 0.f, 0.f, 0.f};
        acc = __builtin_amdgcn_mfma_f32_16x16x32_f16(a0, b0, acc, 0, 0, 0);
        acc = __builtin_amdgcn_mfma_f32_16x16x32_f16(a1, b1, acc, 0, 0, 0);

        const int   cl  = t * 16 + col;
        const float c2v = c2s[cl];
        float fl[4];
#pragma unroll
        for (int i = 0; i < 4; ++i) {
            float dp = fmaf(-2.0f, acc[i], c2v);        // dist minus x2 (const per row)
            float lose = dp < m1d[i] ? m1d[i] : dp;
            m2r[i] = fminf(m2r[i], lose);
            m1c[i] = dp < m1d[i] ? (unsigned)cl : m1c[i];
            m1d[i] = fminf(m1d[i], dp);
            fl[i] = dp + x2r[i];                        // full dist for per-code min
        }
        float pf = fminf(fminf(fl[0], fl[1]), fminf(fl[2], fl[3]));
        atomicMin(&mcode[cl], __float_as_uint(pf));     // ds_min no-return, off critical path
    }

    // butterfly across the 16 code-lanes (lexicographic, first-index tie-break)
#pragma unroll
    for (int s = 1; s < 16; s <<= 1) {
#pragma unroll
        for (int i = 0; i < 4; ++i) {
            float    od  = __shfl_xor(m1d[i], s);
            unsigned oc  = (unsigned)__shfl_xor((int)m1c[i], s);
            float    om2 = __shfl_xor(m2r[i], s);
            bool lt = (od < m1d[i]) || (od == m1d[i] && oc < m1c[i]);
            float lose = lt ? m1d[i] : od;
            m2r[i] = fminf(fminf(m2r[i], om2), lose);
            if (lt) { m1d[i] = od; m1c[i] = oc; }
        }
    }
    if (col == 0) {
        int pidx = h * 32768 + p0 + w * 16 + rg * 4;
        *(float4*)&m1dA[pidx] = make_float4(m1d[0], m1d[1], m1d[2], m1d[3]);
        *(int4*)  &m1cA[pidx] = make_int4((int)(m1c[0] + cb0), (int)(m1c[1] + cb0),
                                          (int)(m1c[2] + cb0), (int)(m1c[3] + cb0));
        *(float4*)&m2A[pidx]  = make_float4(m2r[0], m2r[1], m2r[2], m2r[3]);
    }
    __syncthreads();   // barrier #2: mcode complete

    {   // flush per-code mins to sharded global
        int sb = (pt & 15) * 1024 + cb0;
        atomicMin(&shard[sb + tid],       mcode[tid]);
        atomicMin(&shard[sb + 256 + tid], mcode[tid + 256]);
    }
}

// ---------------- kmerge: merge halves -> token/bdist/flags/active + ST output ----------------
__global__ __launch_bounds__(256) void vq_kmerge(const float* __restrict__ x,
                                                 const float* __restrict__ cb,
                                                 const float* __restrict__ m1dA,
                                                 const int* __restrict__ m1cA,
                                                 const float* __restrict__ m2A,
                                                 const float* __restrict__ x2a,
                                                 int* __restrict__ token,
                                                 float* __restrict__ bdist,
                                                 int* __restrict__ active,
                                                 int* __restrict__ gflag,
                                                 unsigned* __restrict__ fcnt,
                                                 float* __restrict__ outp) {
    __shared__ int toksh[256];
    const int tid = threadIdx.x;
    const int p   = blockIdx.x * 256 + tid;   // grid 128

    float d0 = m1dA[p],         d1 = m1dA[32768 + p];
    int   c0 = m1cA[p],         c1 = m1cA[32768 + p];
    float s0 = m2A[p],          s1 = m2A[32768 + p];
    float lose = d1 < d0 ? d0 : d1;
    float m2 = fminf(fminf(s0, s1), lose);
    float bd = fminf(d0, d1);
    int   bc = d1 < d0 ? c1 : c0;             // tie -> half 0 (lower code)
    token[p] = bc;
    toksh[tid] = bc;
    bdist[p] = bd + x2a[p];
    atomicAdd(&active[bc], 1);
    if (m2 - bd <= EPS) {                     // near-tie: exact resolution needed
        unsigned ix = atomicAdd(fcnt, 1u);
        if (ix < FCAP) gflag[ix] = p;
    }
    __syncthreads();

    // straight-through output for this block's 256 points (coalesced float4)
#pragma unroll
    for (int it = 0; it < 16; ++it) {
        int g = blockIdx.x * 4096 + it * 256 + tid;
        int pl = (it * 256 + tid) >> 4, q = g & 15;
        int tok = toksh[pl];
        float4 xv = ((const float4*)x)[g];
        float4 cv = ((const float4*)cb)[tok * 16 + q];
        float4 o;
        o.x = xv.x + (cv.x - xv.x);
        o.y = xv.y + (cv.y - xv.y);
        o.z = xv.z + (cv.z - xv.z);
        o.w = xv.w + (cv.w - xv.w);
        ((float4*)outp)[g] = o;
    }
}

// ---------------- kfix: exact fp32 rescan for flagged points (+fix out/active) ----------------
__global__ __launch_bounds__(256) void vq_kfix(const float* __restrict__ x,
                                               const float* __restrict__ cb,
                                               const float* __restrict__ cbT,
                                               const float* __restrict__ c2,
                                               const int* __restrict__ gflag,
                                               const unsigned* __restrict__ fcnt,
                                               int* __restrict__ token,
                                               float* __restrict__ bdist,
                                               int* __restrict__ active,
                                               float* __restrict__ outp) {
    __shared__ float xl[64];
    __shared__ u64t red[256];
    __shared__ u64t bestSh;
    const int tid = threadIdx.x;
    unsigned nf = fcnt[0]; if (nf > FCAP) nf = FCAP;

    for (unsigned fi = blockIdx.x; fi < nf; fi += gridDim.x) {   // grid 256
        int p = gflag[fi];
        __syncthreads();
        if (tid < 64) xl[tid] = x[(size_t)p * 64 + tid];
        __syncthreads();
        float x2v = 0.f;   // exact x2: sequential fma, reference association
#pragma unroll
        for (int d = 0; d < 64; ++d) x2v = fmaf(xl[d], xl[d], x2v);
        float s0 = 0.f, s1 = 0.f, s2 = 0.f, s3 = 0.f;
#pragma unroll
        for (int d = 0; d < 64; ++d) {
            float xv = xl[d];
            s0 = fmaf(xv, cbT[d * 1024 +   0 + tid], s0);
            s1 = fmaf(xv, cbT[d * 1024 + 256 + tid], s1);
            s2 = fmaf(xv, cbT[d * 1024 + 512 + tid], s2);
            s3 = fmaf(xv, cbT[d * 1024 + 768 + tid], s3);
        }
        float d0 = (x2v - 2.f * s0) + c2[tid];
        float d1 = (x2v - 2.f * s1) + c2[tid + 256];
        float d2 = (x2v - 2.f * s2) + c2[tid + 512];
        float d3 = (x2v - 2.f * s3) + c2[tid + 768];
        u64t bb = ~0ull, pk;
        pk = ((u64t)__float_as_uint(d0) << 32) | (unsigned)(tid);       if (pk < bb) bb = pk;
        pk = ((u64t)__float_as_uint(d1) << 32) | (unsigned)(tid + 256); if (pk < bb) bb = pk;
        pk = ((u64t)__float_as_uint(d2) << 32) | (unsigned)(tid + 512); if (pk < bb) bb = pk;
        pk = ((u64t)__float_as_uint(d3) << 32) | (unsigned)(tid + 768); if (pk < bb) bb = pk;
        red[tid] = bb;
        __syncthreads();
        for (int s = 128; s > 0; s >>= 1) {
            if (tid < s) { u64t o = red[tid + s]; if (o < red[tid]) red[tid] = o; }
            __syncthreads();
        }
        if (tid == 0) {
            u64t b = red[0];
            bestSh = b;
            int newc = (int)(unsigned)(b & 0xFFFFFFFFu);
            int oldc = token[p];
            token[p] = newc;
            bdist[p] = hi_f(b);
            if (newc != oldc) {
                atomicAdd(&active[oldc], -1);
                atomicAdd(&active[newc], 1);
            }
        }
        __syncthreads();
        int newc = (int)(unsigned)(bestSh & 0xFFFFFFFFu);
        if (tid < 64) {   // patch the output row
            float xv = xl[tid];
            float cv = cb[(size_t)newc * 64 + tid];
            outp[(size_t)p * 64 + tid] = xv + (cv - xv);
        }
    }
}

// ---------------- k3f: shard merge + entropy + bdist sum + final loss ----------------
__global__ __launch_bounds__(1024) void vq_k3f(const unsigned* __restrict__ shard,
                                               const int* __restrict__ active,
                                               const float* __restrict__ bdist,
                                               float* __restrict__ out_loss) {
    __shared__ double red[1024];
    __shared__ double entS;
    const int t = threadIdx.x;

    unsigned m = 0x7F800000u;
#pragma unroll
    for (int s = 0; s < 16; ++s) m = min(m, shard[s * 1024 + t]);
    red[t] = (active[t] == 0) ? (double)__uint_as_float(m) : 0.0;
    __syncthreads();
    for (int s = 512; s > 0; s >>= 1) {
        if (t < s) red[t] += red[t + s];
        __syncthreads();
    }
    if (t == 0) entS = red[0];
    __syncthreads();

    double acc = 0.0;
#pragma unroll
    for (int k = 0; k < 32; ++k) acc += (double)bdist[k * 1024 + t];
    red[t] = acc;
    __syncthreads();
    for (int s = 512; s > 0; s >>= 1) {
        if (t < s) red[t] += red[t + s];
        __syncthreads();
    }
    if (t == 0) {
        double mean_sq = red[0] / (double)(32768ll * 64);
        double total = 1.25 * mean_sq + 0.01 * (entS / 1024.0);
        out_loss[0] = (float)total;
    }
}

extern "C" void kernel_launch(void* const* d_in, const int* in_sizes, int n_in,
                              void* d_out, int out_size, void* d_ws, size_t ws_size,
                              hipStream_t stream) {
    const float* x  = (const float*)d_in[0];
    const float* cb = (const float*)d_in[1];
    float* out = (float*)d_out;
    char* ws = (char*)d_ws;

    float*          m1dA   = (float*)(ws + WS_M1D);
    int*            m1cA   = (int*)(ws + WS_M1C);
    float*          m2A    = (float*)(ws + WS_M2);
    float*          x2a    = (float*)(ws + WS_X2);
    int*            token  = (int*)(ws + WS_TOKEN);
    float*          bdist  = (float*)(ws + WS_BDIST);
    unsigned short* pcb    = (unsigned short*)(ws + WS_PCB);
    float*          cbT    = (float*)(ws + WS_CBT);
    float*          c2     = (float*)(ws + WS_C2);
    unsigned*       shard  = (unsigned*)(ws + WS_SHARD);
    int*            active = (int*)(ws + WS_ACT);
    int*            gflag  = (int*)(ws + WS_FLAG);
    unsigned*       fcnt   = (unsigned*)(ws + WS_FCNT);

    vq_k0    <<<64,   256, 0, stream>>>(cb, shard, active, c2, pcb, cbT, fcnt);
    vq_k1    <<<1024, 256, 0, stream>>>(x, c2, pcb, shard, m1dA, m1cA, m2A, x2a);
    vq_kmerge<<<128,  256, 0, stream>>>(x, cb, m1dA, m1cA, m2A, x2a, token, bdist,
                                        active, gflag, fcnt, out);
    vq_kfix  <<<256,  256, 0, stream>>>(x, cb, cbT, c2, gflag, fcnt, token, bdist,
                                        active, out);
    vq_k3f   <<<1,   1024, 0, stream>>>(shard, active, bdist, out + 2097152);
}

// Round 7
// 48.650 us; speedup vs baseline: 4.7985x; 1.1204x over previous
//
#include <hip/hip_runtime.h>
#include <hip/hip_fp16.h>
#include <stdint.h>

typedef float f32x4 __attribute__((ext_vector_type(4)));
typedef _Float16 f16x8 __attribute__((ext_vector_type(8)));
typedef unsigned short us8 __attribute__((ext_vector_type(8)));
typedef unsigned long long u64t;

#define EPS  3.0e-3f
#define FCAP 8192

// ws layout (bytes)
#define WS_TOKEN 0         // int[32768]
#define WS_BDIST 131072    // float[32768]
#define WS_PCB   262144    // ushort[65536] fp16 frag-linear codebook
#define WS_CBT   393216    // float[65536] cb transposed [d][c]
#define WS_C2    655360    // float[1024]
#define WS_SHARD 659456    // u32[16*1024]
#define WS_ACT   724992    // int[1024]
#define WS_FLAG  729088    // int[8192]
#define WS_FCNT  761856    // u32[64]

__device__ __forceinline__ float hi_f(u64t v) {
    return __uint_as_float((unsigned)(v >> 32));
}

// ---------------- k0: init + fp16 frag-linear codebook + cbT + c2 ----------------
__global__ __launch_bounds__(256) void vq_k0(const float* __restrict__ cb,
                                             unsigned* __restrict__ shard,
                                             int* __restrict__ active,
                                             float* __restrict__ c2,
                                             unsigned short* __restrict__ pcb,
                                             float* __restrict__ cbT,
                                             unsigned* __restrict__ fcnt) {
    int g = blockIdx.x * 256 + threadIdx.x;   // grid 64 -> 16384
    shard[g] = 0x7F800000u;                   // 16*1024 entries
    if (g < 64) fcnt[g] = 0;
    if (g < 1024) {
        active[g] = 0;
        const float4* row = (const float4*)(cb + g * 64);
        float s = 0.f;
#pragma unroll
        for (int q = 0; q < 16; ++q) {
            float4 v = row[q];
            s = fmaf(v.x, v.x, s); s = fmaf(v.y, v.y, s);
            s = fmaf(v.z, v.z, s); s = fmaf(v.w, v.w, s);
        }
        c2[g] = s;
    }
    if (g < 8192) {   // fp16 frag-linear: unit = (code c, 8-elem d-chunk u)
        int c = g >> 3, u = g & 7;
        const float4* row = (const float4*)(cb + c * 64);
        float4 v0 = row[u * 2], v1 = row[u * 2 + 1];
        us8 o;
        o[0] = __half_as_ushort(__float2half_rn(v0.x));
        o[1] = __half_as_ushort(__float2half_rn(v0.y));
        o[2] = __half_as_ushort(__float2half_rn(v0.z));
        o[3] = __half_as_ushort(__float2half_rn(v0.w));
        o[4] = __half_as_ushort(__float2half_rn(v1.x));
        o[5] = __half_as_ushort(__float2half_rn(v1.y));
        o[6] = __half_as_ushort(__float2half_rn(v1.z));
        o[7] = __half_as_ushort(__float2half_rn(v1.w));
        int frag  = (c >> 4) * 2 + (u >> 2);
        int lane8 = (c & 15) + 16 * (u & 3);
        *(us8*)&pcb[frag * 512 + lane8 * 8] = o;
    }
    {   // transpose: cbT[d][c] = cb[c][d]
        int c = g & 1023, seg = g >> 10;
        float4 v = ((const float4*)(cb + c * 64))[seg];
        cbT[(seg * 4 + 0) * 1024 + c] = v.x;
        cbT[(seg * 4 + 1) * 1024 + c] = v.y;
        cbT[(seg * 4 + 2) * 1024 + c] = v.z;
        cbT[(seg * 4 + 3) * 1024 + c] = v.w;
    }
}

// ---------------- k1: 1024-thread block, 64 pts x full codebook, in-block merge,
//                      fused straight-through output ----------------
// grid 512 -> 2 blocks/CU -> 32 waves/CU. wave (pg = w&3: 16 pts, cq = w>>2: 256 codes).
__global__ __launch_bounds__(1024, 8) void vq_k1(const float* __restrict__ x,
                                                 const float* __restrict__ cb,
                                                 const float* __restrict__ c2g,
                                                 const unsigned short* __restrict__ pcb,
                                                 unsigned* __restrict__ shard,
                                                 int* __restrict__ token,
                                                 float* __restrict__ bdist,
                                                 int* __restrict__ active,
                                                 int* __restrict__ gflag,
                                                 unsigned* __restrict__ fcnt,
                                                 float* __restrict__ outp) {
    __shared__ __align__(16) unsigned short aF[4096];  // 8KB fp16 x-frags (64 pts)
    __shared__ float    c2s[1024];
    __shared__ unsigned mcode[1024];                   // block-wide per-code min (dist bits)
    __shared__ float    x2s[64];
    __shared__ float    wd[4][64];
    __shared__ int      wc[4][64];
    __shared__ float    wm[4][64];
    __shared__ int      toksh[64];

    const int tid  = threadIdx.x;
    const int lane = tid & 63;
    const int w    = tid >> 6;
    const int col  = lane & 15;
    const int rg   = lane >> 4;
    const int pg   = w & 3;        // point group (16 pts)
    const int cq   = w >> 2;       // code quarter (256 codes)
    const int p0   = blockIdx.x * 64;

    // stage x -> fp16 frag-linear LDS + x2 (threads 0-255, as verified in r5/r6)
    if (tid < 256) {
        int r = tid >> 2, sg = tid & 3;
        const float4* xr4 = (const float4*)(x + (size_t)(p0 + r) * 64) + sg * 4;
        float4 v0 = xr4[0], v1 = xr4[1], v2 = xr4[2], v3 = xr4[3];
        float s = 0.f;
        s = fmaf(v0.x, v0.x, s); s = fmaf(v0.y, v0.y, s); s = fmaf(v0.z, v0.z, s); s = fmaf(v0.w, v0.w, s);
        s = fmaf(v1.x, v1.x, s); s = fmaf(v1.y, v1.y, s); s = fmaf(v1.z, v1.z, s); s = fmaf(v1.w, v1.w, s);
        s = fmaf(v2.x, v2.x, s); s = fmaf(v2.y, v2.y, s); s = fmaf(v2.z, v2.z, s); s = fmaf(v2.w, v2.w, s);
        s = fmaf(v3.x, v3.x, s); s = fmaf(v3.y, v3.y, s); s = fmaf(v3.z, v3.z, s); s = fmaf(v3.w, v3.w, s);
        s += __shfl_xor(s, 1);
        s += __shfl_xor(s, 2);
        if (sg == 0) x2s[r] = s;

        us8 o0, o1;
        o0[0]=__half_as_ushort(__float2half_rn(v0.x)); o0[1]=__half_as_ushort(__float2half_rn(v0.y));
        o0[2]=__half_as_ushort(__float2half_rn(v0.z)); o0[3]=__half_as_ushort(__float2half_rn(v0.w));
        o0[4]=__half_as_ushort(__float2half_rn(v1.x)); o0[5]=__half_as_ushort(__float2half_rn(v1.y));
        o0[6]=__half_as_ushort(__float2half_rn(v1.z)); o0[7]=__half_as_ushort(__float2half_rn(v1.w));
        o1[0]=__half_as_ushort(__float2half_rn(v2.x)); o1[1]=__half_as_ushort(__float2half_rn(v2.y));
        o1[2]=__half_as_ushort(__float2half_rn(v2.z)); o1[3]=__half_as_ushort(__float2half_rn(v2.w));
        o1[4]=__half_as_ushort(__float2half_rn(v3.x)); o1[5]=__half_as_ushort(__float2half_rn(v3.y));
        o1[6]=__half_as_ushort(__float2half_rn(v3.z)); o1[7]=__half_as_ushort(__float2half_rn(v3.w));
        int u0 = 2 * sg, u1 = 2 * sg + 1;
        int f0 = (r >> 4) * 2 + (u0 >> 2), l0 = (r & 15) + 16 * (u0 & 3);
        int f1 = (r >> 4) * 2 + (u1 >> 2), l1 = (r & 15) + 16 * (u1 & 3);
        *(us8*)&aF[f0 * 512 + l0 * 8] = o0;
        *(us8*)&aF[f1 * 512 + l1 * 8] = o1;
    }
    c2s[tid]   = c2g[tid];
    mcode[tid] = 0x7F800000u;
    __syncthreads();   // barrier #1: aF/x2s/c2s/mcode ready

    f16x8 a0 = *(const f16x8*)&aF[(pg * 2 + 0) * 512 + lane * 8];
    f16x8 a1 = *(const f16x8*)&aF[(pg * 2 + 1) * 512 + lane * 8];

    float x2r[4];
#pragma unroll
    for (int i = 0; i < 4; ++i) x2r[i] = x2s[pg * 16 + rg * 4 + i];

    float    m1d[4], m2r[4];
    unsigned m1c[4];
#pragma unroll
    for (int i = 0; i < 4; ++i) { m1d[i] = 3.4e38f; m2r[i] = 3.4e38f; m1c[i] = 0; }

    const f16x8* pb = (const f16x8*)pcb;

    // main loop: 16 tiles of 16 codes (this wave's quarter), shuffle-free epilogue
#pragma unroll 8
    for (int t = 0; t < 16; ++t) {
        const int ct = cq * 16 + t;                     // global code-tile
        f16x8 b0 = pb[(ct * 2 + 0) * 64 + lane];
        f16x8 b1 = pb[(ct * 2 + 1) * 64 + lane];
        f32x4 acc = (f32x4){0.f, 0.f, 0.f, 0.f};
        acc = __builtin_amdgcn_mfma_f32_16x16x32_f16(a0, b0, acc, 0, 0, 0);
        acc = __builtin_amdgcn_mfma_f32_16x16x32_f16(a1, b1, acc, 0, 0, 0);

        const int   cl  = ct * 16 + col;                // global code
        const float c2v = c2s[cl];
        float fl[4];
#pragma unroll
        for (int i = 0; i < 4; ++i) {
            float dp = fmaf(-2.0f, acc[i], c2v);        // dist minus x2 (const per row)
            float lose = dp < m1d[i] ? m1d[i] : dp;
            m2r[i] = fminf(m2r[i], lose);
            m1c[i] = dp < m1d[i] ? (unsigned)cl : m1c[i];   // codes increase: ties keep old
            m1d[i] = fminf(m1d[i], dp);
            fl[i] = dp + x2r[i];                        // full dist for per-code min
        }
        float pf = fminf(fminf(fl[0], fl[1]), fminf(fl[2], fl[3]));
        atomicMin(&mcode[cl], __float_as_uint(pf));     // ds_min no-return, off critical path
    }

    // butterfly across the 16 code-lanes (lexicographic, first-index tie-break)
#pragma unroll
    for (int s = 1; s < 16; s <<= 1) {
#pragma unroll
        for (int i = 0; i < 4; ++i) {
            float    od  = __shfl_xor(m1d[i], s);
            unsigned oc  = (unsigned)__shfl_xor((int)m1c[i], s);
            float    om2 = __shfl_xor(m2r[i], s);
            bool lt = (od < m1d[i]) || (od == m1d[i] && oc < m1c[i]);
            float lose = lt ? m1d[i] : od;
            m2r[i] = fminf(fminf(m2r[i], om2), lose);
            if (lt) { m1d[i] = od; m1c[i] = oc; }
        }
    }
    if (col == 0) {
#pragma unroll
        for (int i = 0; i < 4; ++i) {
            int pr = pg * 16 + rg * 4 + i;
            wd[cq][pr] = m1d[i];
            wc[cq][pr] = (int)m1c[i];
            wm[cq][pr] = m2r[i];
        }
    }
    __syncthreads();   // barrier #2: wred + mcode complete

    // threads 0-63: merge the 4 quarters (ascending -> lowest-code tie-break)
    if (tid < 64) {
        float bd = wd[0][tid]; int bc = wc[0][tid]; float m2 = wm[0][tid];
#pragma unroll
        for (int q = 1; q < 4; ++q) {
            float od = wd[q][tid]; int oc = wc[q][tid]; float om2 = wm[q][tid];
            float lose = od < bd ? bd : od;
            m2 = fminf(fminf(m2, om2), lose);
            if (od < bd) { bd = od; bc = oc; }
        }
        int p = p0 + tid;
        token[p]   = bc;
        toksh[tid] = bc;
        bdist[p]   = bd + x2s[tid];
        atomicAdd(&active[bc], 1);
        if (m2 - bd <= EPS) {                 // near-tie: exact resolution needed
            unsigned ix = atomicAdd(fcnt, 1u);
            if (ix < FCAP) gflag[ix] = p;
        }
    }
    {   // flush block per-code mins to sharded global (1 atomic/thread)
        atomicMin(&shard[(blockIdx.x & 15) * 1024 + tid], mcode[tid]);
    }
    __syncthreads();   // barrier #3: toksh ready

    // fused straight-through output: 64 pts x 16 float4 = 1024 float4 (1/thread)
    {
        int g  = blockIdx.x * 1024 + tid;     // global float4 index
        int pl = tid >> 4, q = tid & 15;
        int tok = toksh[pl];
        float4 xv = ((const float4*)x)[g];
        float4 cv = ((const float4*)cb)[tok * 16 + q];
        float4 o;
        o.x = xv.x + (cv.x - xv.x);
        o.y = xv.y + (cv.y - xv.y);
        o.z = xv.z + (cv.z - xv.z);
        o.w = xv.w + (cv.w - xv.w);
        ((float4*)outp)[g] = o;
    }
}

// ---------------- kfix: exact fp32 rescan for flagged points (+fix out/active) ----------------
__global__ __launch_bounds__(256) void vq_kfix(const float* __restrict__ x,
                                               const float* __restrict__ cb,
                                               const float* __restrict__ cbT,
                                               const float* __restrict__ c2,
                                               const int* __restrict__ gflag,
                                               const unsigned* __restrict__ fcnt,
                                               int* __restrict__ token,
                                               float* __restrict__ bdist,
                                               int* __restrict__ active,
                                               float* __restrict__ outp) {
    __shared__ float xl[64];
    __shared__ u64t red[256];
    __shared__ u64t bestSh;
    const int tid = threadIdx.x;
    unsigned nf = fcnt[0]; if (nf > FCAP) nf = FCAP;

    for (unsigned fi = blockIdx.x; fi < nf; fi += gridDim.x) {   // grid 256
        int p = gflag[fi];
        __syncthreads();
        if (tid < 64) xl[tid] = x[(size_t)p * 64 + tid];
        __syncthreads();
        float x2v = 0.f;   // exact x2: sequential fma, reference association
#pragma unroll
        for (int d = 0; d < 64; ++d) x2v = fmaf(xl[d], xl[d], x2v);
        float s0 = 0.f, s1 = 0.f, s2 = 0.f, s3 = 0.f;
#pragma unroll
        for (int d = 0; d < 64; ++d) {
            float xv = xl[d];
            s0 = fmaf(xv, cbT[d * 1024 +   0 + tid], s0);
            s1 = fmaf(xv, cbT[d * 1024 + 256 + tid], s1);
            s2 = fmaf(xv, cbT[d * 1024 + 512 + tid], s2);
            s3 = fmaf(xv, cbT[d * 1024 + 768 + tid], s3);
        }
        float d0 = (x2v - 2.f * s0) + c2[tid];
        float d1 = (x2v - 2.f * s1) + c2[tid + 256];
        float d2 = (x2v - 2.f * s2) + c2[tid + 512];
        float d3 = (x2v - 2.f * s3) + c2[tid + 768];
        u64t bb = ~0ull, pk;
        pk = ((u64t)__float_as_uint(d0) << 32) | (unsigned)(tid);       if (pk < bb) bb = pk;
        pk = ((u64t)__float_as_uint(d1) << 32) | (unsigned)(tid + 256); if (pk < bb) bb = pk;
        pk = ((u64t)__float_as_uint(d2) << 32) | (unsigned)(tid + 512); if (pk < bb) bb = pk;
        pk = ((u64t)__float_as_uint(d3) << 32) | (unsigned)(tid + 768); if (pk < bb) bb = pk;
        red[tid] = bb;
        __syncthreads();
        for (int s = 128; s > 0; s >>= 1) {
            if (tid < s) { u64t o = red[tid + s]; if (o < red[tid]) red[tid] = o; }
            __syncthreads();
        }
        if (tid == 0) {
            u64t b = red[0];
            bestSh = b;
            int newc = (int)(unsigned)(b & 0xFFFFFFFFu);
            int oldc = token[p];
            token[p] = newc;
            bdist[p] = hi_f(b);
            if (newc != oldc) {
                atomicAdd(&active[oldc], -1);
                atomicAdd(&active[newc], 1);
            }
        }
        __syncthreads();
        int newc = (int)(unsigned)(bestSh & 0xFFFFFFFFu);
        if (tid < 64) {   // patch the output row
            float xv = xl[tid];
            float cv = cb[(size_t)newc * 64 + tid];
            outp[(size_t)p * 64 + tid] = xv + (cv - xv);
        }
    }
}

// ---------------- k3f: shard merge + entropy + bdist sum + final loss ----------------
__global__ __launch_bounds__(1024) void vq_k3f(const unsigned* __restrict__ shard,
                                               const int* __restrict__ active,
                                               const float* __restrict__ bdist,
                                               float* __restrict__ out_loss) {
    __shared__ double red[1024];
    __shared__ double entS;
    const int t = threadIdx.x;

    unsigned m = 0x7F800000u;
#pragma unroll
    for (int s = 0; s < 16; ++s) m = min(m, shard[s * 1024 + t]);
    red[t] = (active[t] == 0) ? (double)__uint_as_float(m) : 0.0;
    __syncthreads();
    for (int s = 512; s > 0; s >>= 1) {
        if (t < s) red[t] += red[t + s];
        __syncthreads();
    }
    if (t == 0) entS = red[0];
    __syncthreads();

    double acc = 0.0;
#pragma unroll
    for (int k = 0; k < 32; ++k) acc += (double)bdist[k * 1024 + t];
    red[t] = acc;
    __syncthreads();
    for (int s = 512; s > 0; s >>= 1) {
        if (t < s) red[t] += red[t + s];
        __syncthreads();
    }
    if (t == 0) {
        double mean_sq = red[0] / (double)(32768ll * 64);
        double total = 1.25 * mean_sq + 0.01 * (entS / 1024.0);
        out_loss[0] = (float)total;
    }
}

extern "C" void kernel_launch(void* const* d_in, const int* in_sizes, int n_in,
                              void* d_out, int out_size, void* d_ws, size_t ws_size,
                              hipStream_t stream) {
    const float* x  = (const float*)d_in[0];
    const float* cb = (const float*)d_in[1];
    float* out = (float*)d_out;
    char* ws = (char*)d_ws;

    int*            token  = (int*)(ws + WS_TOKEN);
    float*          bdist  = (float*)(ws + WS_BDIST);
    unsigned short* pcb    = (unsigned short*)(ws + WS_PCB);
    float*          cbT    = (float*)(ws + WS_CBT);
    float*          c2     = (float*)(ws + WS_C2);
    unsigned*       shard  = (unsigned*)(ws + WS_SHARD);
    int*            active = (int*)(ws + WS_ACT);
    int*            gflag  = (int*)(ws + WS_FLAG);
    unsigned*       fcnt   = (unsigned*)(ws + WS_FCNT);

    vq_k0  <<<64,   256, 0, stream>>>(cb, shard, active, c2, pcb, cbT, fcnt);
    vq_k1  <<<512, 1024, 0, stream>>>(x, cb, c2, pcb, shard, token, bdist,
                                      active, gflag, fcnt, out);
    vq_kfix<<<256,  256, 0, stream>>>(x, cb, cbT, c2, gflag, fcnt, token, bdist,
                                      active, out);
    vq_k3f <<<1,   1024, 0, stream>>>(shard, active, bdist, out + 2097152);
}